// Round 4
// baseline (410.196 us; speedup 1.0000x reference)
//
#include <hip/hip_runtime.h>
#include <cstdint>
#include <cstddef>

#define EPSV 1e-5f
#define GK 2048

typedef __bf16 bf16x8 __attribute__((ext_vector_type(8)));
typedef float f32x4 __attribute__((ext_vector_type(4)));

__device__ __forceinline__ unsigned short f2bf(float f) {
  unsigned int u = __float_as_uint(f);
  u += 0x7FFFu + ((u >> 16) & 1u);   // round-to-nearest-even
  return (unsigned short)(u >> 16);
}

__device__ __forceinline__ void async_copy16(const void* src, void* dst_lds) {
  __builtin_amdgcn_global_load_lds(
      (const __attribute__((address_space(1))) void*)src,
      (__attribute__((address_space(3))) void*)dst_lds, 16, 0, 0);
}

// ---------------- pool: register-direct MFMA part-pooling ------------------
// Grid 2048 (b = blk>>5, 64-channel block = blk&31). Each wave owns 16
// channels; A-fragment loaded straight from global (2 x float4 per lane per
// k-step, line-coalesced), one-hot B-fragment built in registers from a
// 256-byte pid LDS array (broadcast ds_read_b64). LDS ~0.3KB, no staging,
// no bank conflicts, native v_cvt_pk_bf16_f32 conversions.
__global__ __launch_bounds__(256) void pool(
    const float* __restrict__ x, const int* __restrict__ mask,
    unsigned short* __restrict__ Abuf) {
  __shared__ unsigned char pid8[256];
  __shared__ int cnt[10];
  const int t = threadIdx.x;
  const int b = blockIdx.x >> 5;
  const int c0 = (blockIdx.x & 31) * 64;

  int m = mask[(size_t)b * 65536 + (t >> 4) * 4096 + (t & 15) * 16];
  if (t < 10) cnt[t] = 0;
  __syncthreads();
  atomicAdd(&cnt[m], 1);
  pid8[t] = (unsigned char)m;
  __syncthreads();

  const int w = t >> 6;
  const int l16 = t & 15;
  const int quad = (t & 63) >> 4;
  const float* xrow = x + ((size_t)(b * 2048 + c0 + w * 16 + l16)) * 256;
  const unsigned int tgt = (unsigned int)(l16 + 1);

  f32x4 acc = (f32x4){0.f, 0.f, 0.f, 0.f};
#pragma unroll
  for (int ks = 0; ks < 8; ks++) {
    const float4 va = *(const float4*)(xrow + ks * 32 + quad * 8);
    const float4 vb = *(const float4*)(xrow + ks * 32 + quad * 8 + 4);
    uint2 pc = *(const uint2*)&pid8[ks * 32 + quad * 8];
    union { bf16x8 v; unsigned int u[4]; } bfr;
#pragma unroll
    for (int d = 0; d < 4; d++) {
      unsigned int word = (d < 2) ? pc.x : pc.y;
      unsigned int sh = (d & 1) * 16;
      unsigned int b0 = (word >> sh) & 0xFFu;
      unsigned int b1 = (word >> (sh + 8)) & 0xFFu;
      bfr.u[d] = (b0 == tgt ? 0x3F80u : 0u) | (b1 == tgt ? 0x3F800000u : 0u);
    }
    bf16x8 af;
    af[0] = (__bf16)va.x; af[1] = (__bf16)va.y;
    af[2] = (__bf16)va.z; af[3] = (__bf16)va.w;
    af[4] = (__bf16)vb.x; af[5] = (__bf16)vb.y;
    af[6] = (__bf16)vb.z; af[7] = (__bf16)vb.w;
    acc = __builtin_amdgcn_mfma_f32_16x16x32_bf16(af, bfr.v, acc, 0, 0, 0);
  }

  if (l16 < 9) {
    const int p = l16;
    float invp = 1.f / ((float)cnt[p + 1] + 1e-8f);
    int dm1 = 0;
#pragma unroll
    for (int q = 8; q >= 0; q--)
      if (cnt[q + 1] > 0) dm1 = q;
    int cbase = c0 + w * 16 + quad * 4;
    ushort4 hm;
    hm.x = f2bf(acc[0] * invp);
    hm.y = f2bf(acc[1] * invp);
    hm.z = f2bf(acc[2] * invp);
    hm.w = f2bf(acc[3] * invp);
    ushort4 hs = (p == dm1) ? (ushort4){0, 0, 0, 0} : hm;
    *(ushort4*)&Abuf[(size_t)(b * 9 + p) * 2048 + cbase] = hm;
    *(ushort4*)&Abuf[(size_t)((64 + b) * 9 + p) * 2048 + cbase] = hs;
  }
}

// ---------------- prep: Wt transpose + global-mean BN + BN sc/sh fold ------
// blocks [0,8192):      transpose W1/W2 (fp32 KxN) -> Wt (bf16 NxK)
// blocks [8192,16384):  feat_global mean+BN, 16 rows/block (4 rows/wave ILP)
// blocks [16384,16528): BN fold: sc = g*rsqrt(rv+eps), sh = (bias-rm)*sc+be
// Max LDS = 4.2KB transpose tile -> high occupancy for the streaming blocks.
__global__ __launch_bounds__(256) void prep(
    const float* __restrict__ W1, const float* __restrict__ W2,
    unsigned short* __restrict__ Wt1, unsigned short* __restrict__ Wt2,
    const float* __restrict__ xg, const float* __restrict__ gb_g,
    const float* __restrict__ gb_b, const float* __restrict__ gb_rm,
    const float* __restrict__ gb_rv, float* __restrict__ out,
    const float* __restrict__ b1, const float* __restrict__ g1,
    const float* __restrict__ be1, const float* __restrict__ rm1,
    const float* __restrict__ rv1, const float* __restrict__ b2,
    const float* __restrict__ g2, const float* __restrict__ be2,
    const float* __restrict__ rm2, const float* __restrict__ rv2,
    float* __restrict__ sc1, float* __restrict__ sh1,
    float* __restrict__ sc2, float* __restrict__ sh2) {
  __shared__ float tile[32][33];
  const int blk = blockIdx.x;
  const int t = threadIdx.x;

  if (blk < 8192) {
    int z = blk >> 12;
    int rem = blk & 4095;
    int by = rem >> 6, bx = rem & 63;
    const float* W = z ? W2 : W1;
    unsigned short* Wt = z ? Wt2 : Wt1;
    int tx = t & 31;
    int ty = t >> 5;  // 0..7
    int k0 = by * 32, n0 = bx * 32;
#pragma unroll
    for (int i = 0; i < 32; i += 8)
      tile[ty + i][tx] = W[(size_t)(k0 + ty + i) * 2048 + n0 + tx];
    __syncthreads();
#pragma unroll
    for (int i = 0; i < 32; i += 8)
      Wt[(size_t)(n0 + ty + i) * 2048 + k0 + tx] = f2bf(tile[tx][ty + i]);
  } else if (blk < 16384) {
    // 4 rows per wave (load ILP=4), 16 rows per block
    int base = (blk - 8192) * 16 + (t >> 6) * 4;
    int lane = t & 63;
    const float4* xp = (const float4*)xg + (size_t)base * 64 + lane;
    float4 v0 = xp[0], v1 = xp[64], v2 = xp[128], v3 = xp[192];
    float s0 = v0.x + v0.y + v0.z + v0.w;
    float s1 = v1.x + v1.y + v1.z + v1.w;
    float s2 = v2.x + v2.y + v2.z + v2.w;
    float s3 = v3.x + v3.y + v3.z + v3.w;
#pragma unroll
    for (int o = 32; o > 0; o >>= 1) {
      s0 += __shfl_xor(s0, o, 64);
      s1 += __shfl_xor(s1, o, 64);
      s2 += __shfl_xor(s2, o, 64);
      s3 += __shfl_xor(s3, o, 64);
    }
    if (lane == 0) {
      int b = base >> 11, c = base & 2047;
      float mm[4] = {s0 * (1.f / 256.f), s1 * (1.f / 256.f),
                     s2 * (1.f / 256.f), s3 * (1.f / 256.f)};
      float4 o4;
      float* po = &o4.x;
#pragma unroll
      for (int r = 0; r < 4; r++) {
        int cc = c + r;
        po[r] = (mm[r] - gb_rm[cc]) / sqrtf(gb_rv[cc] + EPSV) * gb_g[cc] +
                gb_b[cc];
      }
      *(float4*)(out + (size_t)b * 43008 + c) = o4;
    }
  } else {
    int i = (blk - 16384) * 256 + t;  // [0, 36864)
    int z = i >= 18432;
    int f = i - z * 18432;
    int d = f & 2047;
    const float* g = z ? g2 : g1;
    const float* be = z ? be2 : be1;
    const float* rm = z ? rm2 : rm1;
    const float* rv = z ? rv2 : rv1;
    const float* bias = z ? b2 : b1;
    float sc = g[f] / sqrtf(rv[f] + EPSV);
    float sh = (bias[d] - rm[f]) * sc + be[f];
    (z ? sc2 : sc1)[f] = sc;
    (z ? sh2 : sh1)[f] = sh;
  }
}

// ---------------- GEMM: S[M,N] = A[M,K] @ Wt[N,K]^T  (bf16 MFMA) -----------
// 128x64 tile, BK=64 double-buffered, split-K=2 (grid 32x9x2 = 576 blocks).
// 48KB LDS -> 3 blocks/CU (12 waves/CU). XOR-swizzled staging: swizzle on
// the *global source* address so global_load_lds keeps lane-contiguous LDS.
#define SPART (1152 * 2048)
__global__ __launch_bounds__(256) void gemm_db(
    const unsigned short* __restrict__ A, const unsigned short* __restrict__ Bt,
    float* __restrict__ S) {
  __shared__ unsigned short As[2][128 * 64];
  __shared__ unsigned short Bs[2][64 * 64];
  const int tid = threadIdx.x;
  const int lane = tid & 63;
  const int wave = tid >> 6;
  const int wm = (wave >> 1) << 6;  // 0,64
  const int wn = (wave & 1) << 5;   // 0,32
  const int quad = lane >> 4;
  const int l16 = lane & 15;
  const int by = blockIdx.y;
  const int bx = blockIdx.x;
  const int kz = blockIdx.z;

  const unsigned short* Ag = A + (size_t)by * 128 * GK;
  const unsigned short* Bg = Bt + (size_t)bx * 64 * GK;
  S += (size_t)kz * SPART;

  f32x4 acc[4][2];
#pragma unroll
  for (int i = 0; i < 4; i++)
#pragma unroll
    for (int j = 0; j < 2; j++) acc[i][j] = (f32x4){0.f, 0.f, 0.f, 0.f};

  int srA[4], scA[4];
#pragma unroll
  for (int s = 0; s < 4; s++) {
    int idx = tid + s * 256;
    srA[s] = idx >> 3;
    scA[s] = ((idx & 7) ^ (srA[s] & 7)) * 8;
  }
  int srB[2], scB[2];
#pragma unroll
  for (int s = 0; s < 2; s++) {
    int idx = tid + s * 256;
    srB[s] = idx >> 3;
    scB[s] = ((idx & 7) ^ (srB[s] & 7)) * 8;
  }

  const int kbeg = kz * 1024;

#define STAGE(buf, kk)                                                        \
  do {                                                                        \
    _Pragma("unroll") for (int s = 0; s < 4; s++) {                           \
      int idx = tid + s * 256;                                                \
      async_copy16(Ag + (size_t)srA[s] * GK + (kk) + scA[s],                  \
                   &As[buf][idx * 8]);                                        \
    }                                                                         \
    _Pragma("unroll") for (int s = 0; s < 2; s++) {                           \
      int idx = tid + s * 256;                                                \
      async_copy16(Bg + (size_t)srB[s] * GK + (kk) + scB[s],                  \
                   &Bs[buf][idx * 8]);                                        \
    }                                                                         \
  } while (0)

  STAGE(0, kbeg);
  asm volatile("s_waitcnt vmcnt(0)" ::: "memory");
  __syncthreads();

  for (int it = 0; it < 16; it++) {
    const int cur = it & 1;
    if (it < 15) STAGE(cur ^ 1, kbeg + (it + 1) * 64);

#pragma unroll
    for (int ks = 0; ks < 2; ks++) {
      bf16x8 af[4], bfr[2];
#pragma unroll
      for (int i = 0; i < 4; i++) {
        int row = wm + i * 16 + l16;
        int slot = row * 8 + ((ks * 4 + quad) ^ (row & 7));
        af[i] = *(const bf16x8*)&As[cur][slot * 8];
      }
#pragma unroll
      for (int j = 0; j < 2; j++) {
        int row = wn + j * 16 + l16;
        int slot = row * 8 + ((ks * 4 + quad) ^ (row & 7));
        bfr[j] = *(const bf16x8*)&Bs[cur][slot * 8];
      }
#pragma unroll
      for (int i = 0; i < 4; i++)
#pragma unroll
        for (int j = 0; j < 2; j++)
          acc[i][j] = __builtin_amdgcn_mfma_f32_16x16x32_bf16(
              af[i], bfr[j], acc[i][j], 0, 0, 0);
    }

    if (it < 15) {
      asm volatile("s_waitcnt vmcnt(0)" ::: "memory");
      __syncthreads();
    }
  }
#undef STAGE

#pragma unroll
  for (int i = 0; i < 4; i++)
#pragma unroll
    for (int j = 0; j < 2; j++)
#pragma unroll
      for (int r = 0; r < 4; r++) {
        int m = by * 128 + wm + i * 16 + quad * 4 + r;
        int n = bx * 64 + wn + j * 16 + l16;
        S[(size_t)m * 2048 + n] = acc[i][j][r];
      }
}

// ---------------- Epilogue 1: adj-mix + folded BN + ReLU -> A2 (bf16) ------
__global__ __launch_bounds__(256) void epi_mid(
    const float* __restrict__ S, const float* __restrict__ adj,
    const float* __restrict__ sc, const float* __restrict__ sh,
    unsigned short* __restrict__ Aout) {
  int idx = blockIdx.x * 256 + threadIdx.x;  // over 128*2048
  int d = idx & 2047;
  int bb = idx >> 11;
  int b = bb & 63;
  float s[9];
#pragma unroll
  for (int q = 0; q < 9; q++) {
    size_t off = (size_t)(bb * 9 + q) * 2048 + d;
    s[q] = S[off] + S[off + SPART];
  }
#pragma unroll
  for (int p = 0; p < 9; p++) {
    float o = 0.f;
#pragma unroll
    for (int q = 0; q < 9; q++) o += adj[b * 81 + p * 9 + q] * s[q];
    int f = p * 2048 + d;
    float v = fmaxf(o * sc[f] + sh[f], 0.f);
    Aout[(size_t)(bb * 9 + p) * 2048 + d] = f2bf(v);
  }
}

// ---------------- Epilogue 2: adj-mix + folded BN + ReLU -> cats, means, BN -
__global__ __launch_bounds__(256) void epi_final(
    const float* __restrict__ S, const float* __restrict__ adj,
    const float* __restrict__ sc, const float* __restrict__ sh,
    const float* __restrict__ gn_g, const float* __restrict__ gn_b,
    const float* __restrict__ gn_rm, const float* __restrict__ gn_rv,
    float* __restrict__ out) {
  int idx = blockIdx.x * 256 + threadIdx.x;
  int d = idx & 2047;
  int bb = idx >> 11;
  int b = bb & 63;
  bool selfb = bb >= 64;
  float s[9];
#pragma unroll
  for (int q = 0; q < 9; q++) {
    size_t off = (size_t)(bb * 9 + q) * 2048 + d;
    s[q] = S[off] + S[off + SPART];
  }
  float* orow = out + (size_t)b * 43008;
  size_t catbase = selfb ? 24576 : 6144;
  float mean = 0.f;
#pragma unroll
  for (int p = 0; p < 9; p++) {
    float o = 0.f;
#pragma unroll
    for (int q = 0; q < 9; q++) o += adj[b * 81 + p * 9 + q] * s[q];
    int f = p * 2048 + d;
    float v = fmaxf(o * sc[f] + sh[f], 0.f);
    mean += v;
    orow[catbase + f] = v;
  }
  mean *= (1.f / 9.f);
  orow[(selfb ? 4096 : 2048) + d] =
      (mean - gn_rm[d]) / sqrtf(gn_rv[d] + EPSV) * gn_g[d] + gn_b[d];
}

extern "C" void kernel_launch(void* const* d_in, const int* in_sizes, int n_in,
                              void* d_out, int out_size, void* d_ws,
                              size_t ws_size, hipStream_t stream) {
  const float* x_global = (const float*)d_in[0];
  const float* x_gcn = (const float*)d_in[1];
  const int* mask = (const int*)d_in[2];
  const float* adj = (const float*)d_in[3];
  const float* W1 = (const float*)d_in[4];
  const float* b1 = (const float*)d_in[5];
  const float* g1 = (const float*)d_in[6];
  const float* be1 = (const float*)d_in[7];
  const float* rm1 = (const float*)d_in[8];
  const float* rv1 = (const float*)d_in[9];
  const float* W2 = (const float*)d_in[10];
  const float* b2 = (const float*)d_in[11];
  const float* g2 = (const float*)d_in[12];
  const float* be2 = (const float*)d_in[13];
  const float* rm2 = (const float*)d_in[14];
  const float* rv2 = (const float*)d_in[15];
  const float* gb_g = (const float*)d_in[16];
  const float* gb_b = (const float*)d_in[17];
  const float* gb_rm = (const float*)d_in[18];
  const float* gb_rv = (const float*)d_in[19];
  const float* gn_g = (const float*)d_in[20];
  const float* gn_b = (const float*)d_in[21];
  const float* gn_rm = (const float*)d_in[22];
  const float* gn_rv = (const float*)d_in[23];
  float* out = (float*)d_out;

  char* ws = (char*)d_ws;
  unsigned short* Abuf = (unsigned short*)(ws);             // 4,718,592 B
  unsigned short* Wt1 = (unsigned short*)(ws + 4718592);    // 8,388,608 B
  unsigned short* Wt2 = (unsigned short*)(ws + 13107200);   // 8,388,608 B
  float* S = (float*)(ws + 21495808);                       // 18,874,368 B
  float* sc1 = (float*)(ws + 40370176);                     // 73,728 B each
  float* sh1 = (float*)(ws + 40443904);
  float* sc2 = (float*)(ws + 40517632);
  float* sh2 = (float*)(ws + 40591360);

  pool<<<2048, 256, 0, stream>>>(x_gcn, mask, Abuf);
  prep<<<16528, 256, 0, stream>>>(W1, W2, Wt1, Wt2, x_global, gb_g, gb_b,
                                  gb_rm, gb_rv, out, b1, g1, be1, rm1, rv1,
                                  b2, g2, be2, rm2, rv2, sc1, sh1, sc2, sh2);
  gemm_db<<<dim3(32, 9, 2), 256, 0, stream>>>(Abuf, Wt1, S);
  epi_mid<<<1024, 256, 0, stream>>>(S, adj, sc1, sh1, Abuf);
  gemm_db<<<dim3(32, 9, 2), 256, 0, stream>>>(Abuf, Wt2, S);
  epi_final<<<1024, 256, 0, stream>>>(S, adj, sc2, sh2, gn_g, gn_b, gn_rm,
                                      gn_rv, out);
}

// Round 5
// 405.631 us; speedup vs baseline: 1.0113x; 1.0113x over previous
//
#include <hip/hip_runtime.h>
#include <cstdint>
#include <cstddef>

#define EPSV 1e-5f
#define GK 2048

typedef __bf16 bf16x8 __attribute__((ext_vector_type(8)));
typedef float f32x4 __attribute__((ext_vector_type(4)));

__device__ __forceinline__ unsigned short f2bf(float f) {
  unsigned int u = __float_as_uint(f);
  u += 0x7FFFu + ((u >> 16) & 1u);   // round-to-nearest-even
  return (unsigned short)(u >> 16);
}

__device__ __forceinline__ void async_copy16(const void* src, void* dst_lds) {
  __builtin_amdgcn_global_load_lds(
      (const __attribute__((address_space(1))) void*)src,
      (__attribute__((address_space(3))) void*)dst_lds, 16, 0, 0);
}

// ---------------- ingest: all front-end work in ONE launch -----------------
// blocks [0,2048):      part-pooling via MFMA (MEAN branch only; self branch
//                       is derived algebraically in epi_mid), mask stats inline
// blocks [2048,10240):  transpose W1/W2 (fp32 KxN) -> Wt (bf16 NxK)
// blocks [10240,18432): feat_global mean+BN, 16 rows/block (4 rows/wave ILP)
// blocks [18432,18576): BN fold: sc = g*rsqrt(rv+eps), sh = (bias-rm)*sc+be
__global__ __launch_bounds__(256) void ingest(
    const float* __restrict__ x, const int* __restrict__ mask,
    unsigned short* __restrict__ Abuf, int* __restrict__ dropm1,
    const float* __restrict__ W1, const float* __restrict__ W2,
    unsigned short* __restrict__ Wt1, unsigned short* __restrict__ Wt2,
    const float* __restrict__ xg, const float* __restrict__ gb_g,
    const float* __restrict__ gb_b, const float* __restrict__ gb_rm,
    const float* __restrict__ gb_rv, float* __restrict__ out,
    const float* __restrict__ b1, const float* __restrict__ g1,
    const float* __restrict__ be1, const float* __restrict__ rm1,
    const float* __restrict__ rv1, const float* __restrict__ b2,
    const float* __restrict__ g2, const float* __restrict__ be2,
    const float* __restrict__ rm2, const float* __restrict__ rv2,
    float* __restrict__ sc1, float* __restrict__ sh1,
    float* __restrict__ sc2, float* __restrict__ sh2) {
  __shared__ union {
    struct {
      unsigned short As[64 * 264];  // 33792 B
      unsigned short Bs[16 * 264];  // 8448 B
      int pid[256];
      int cnt[10];
      float inv[9];
    } pool;
    float tile[32][33];
  } sm;

  const int blk = blockIdx.x;
  const int t = threadIdx.x;

  if (blk < 2048) {
    // ---- part pooling (mean branch) with inline mask stats ----
    const int b = blk >> 5;
    const int c0 = (blk & 31) * 64;

    int m = mask[(size_t)b * 65536 + (t >> 4) * 4096 + (t & 15) * 16];
    if (t < 10) sm.pool.cnt[t] = 0;
    __syncthreads();
    atomicAdd(&sm.pool.cnt[m], 1);
    sm.pool.pid[t] = m;

    const float4* xgp = (const float4*)(x + ((size_t)(b * 2048 + c0)) * 256);
#pragma unroll
    for (int it = 0; it < 16; it++) {
      int idx = t + it * 256;
      float4 v = xgp[idx];
      int row = idx >> 6, sc = (idx & 63) * 4;
      ushort4 h;
      h.x = f2bf(v.x); h.y = f2bf(v.y); h.z = f2bf(v.z); h.w = f2bf(v.w);
      *(ushort4*)&sm.pool.As[row * 264 + sc] = h;
    }
    __syncthreads();  // cnt, pid, As all final

    {
      int p = t >> 4, s0 = (t & 15) * 16;
#pragma unroll
      for (int j = 0; j < 16; j++)
        sm.pool.Bs[p * 264 + s0 + j] = (sm.pool.pid[s0 + j] == p + 1)
                                           ? (unsigned short)0x3F80
                                           : (unsigned short)0;
    }
    if (t == 0 && (blk & 31) == 0) {
      int dp = 0;
      for (int p = 8; p >= 0; p--)
        if (sm.pool.cnt[p + 1] > 0) dp = p;
      dropm1[b] = dp;
    }
    if (t < 9) sm.pool.inv[t] = 1.f / ((float)sm.pool.cnt[t + 1] + 1e-8f);
    __syncthreads();

    const int wave = t >> 6;
    const int l16 = t & 15;
    const int quad = (t & 63) >> 4;
    f32x4 acc = (f32x4){0.f, 0.f, 0.f, 0.f};
#pragma unroll
    for (int ks = 0; ks < 8; ks++) {
      bf16x8 a =
          *(const bf16x8*)&sm.pool.As[(wave * 16 + l16) * 264 + ks * 32 + quad * 8];
      bf16x8 bf =
          *(const bf16x8*)&sm.pool.Bs[l16 * 264 + ks * 32 + quad * 8];
      acc = __builtin_amdgcn_mfma_f32_16x16x32_bf16(a, bf, acc, 0, 0, 0);
    }

    if (l16 < 9) {
      int p = l16;
      float inv = sm.pool.inv[p];
      int cbase = c0 + wave * 16 + quad * 4;
      ushort4 hm;
      hm.x = f2bf(acc[0] * inv);
      hm.y = f2bf(acc[1] * inv);
      hm.z = f2bf(acc[2] * inv);
      hm.w = f2bf(acc[3] * inv);
      *(ushort4*)&Abuf[(size_t)(b * 9 + p) * 2048 + cbase] = hm;
    }
  } else if (blk < 10240) {
    // ---- W transpose ----
    int rem = blk - 2048;
    int z = rem >> 12;
    rem &= 4095;
    int by = rem >> 6, bx = rem & 63;
    const float* W = z ? W2 : W1;
    unsigned short* Wt = z ? Wt2 : Wt1;
    int tx = t & 31;
    int ty = t >> 5;  // 0..7
    int k0 = by * 32, n0 = bx * 32;
#pragma unroll
    for (int i = 0; i < 32; i += 8)
      sm.tile[ty + i][tx] = W[(size_t)(k0 + ty + i) * 2048 + n0 + tx];
    __syncthreads();
#pragma unroll
    for (int i = 0; i < 32; i += 8)
      Wt[(size_t)(n0 + ty + i) * 2048 + k0 + tx] = f2bf(sm.tile[tx][ty + i]);
  } else if (blk < 18432) {
    // ---- feat_global mean + BN (4 rows/wave ILP, 16 rows/block) ----
    int base = (blk - 10240) * 16 + (t >> 6) * 4;
    int lane = t & 63;
    const float4* xp = (const float4*)xg + (size_t)base * 64 + lane;
    float4 v0 = xp[0], v1 = xp[64], v2 = xp[128], v3 = xp[192];
    float s0 = v0.x + v0.y + v0.z + v0.w;
    float s1 = v1.x + v1.y + v1.z + v1.w;
    float s2 = v2.x + v2.y + v2.z + v2.w;
    float s3 = v3.x + v3.y + v3.z + v3.w;
#pragma unroll
    for (int o = 32; o > 0; o >>= 1) {
      s0 += __shfl_xor(s0, o, 64);
      s1 += __shfl_xor(s1, o, 64);
      s2 += __shfl_xor(s2, o, 64);
      s3 += __shfl_xor(s3, o, 64);
    }
    if (lane == 0) {
      int b = base >> 11, c = base & 2047;
      float mm[4] = {s0 * (1.f / 256.f), s1 * (1.f / 256.f),
                     s2 * (1.f / 256.f), s3 * (1.f / 256.f)};
      float4 o4;
      float* po = &o4.x;
#pragma unroll
      for (int r = 0; r < 4; r++) {
        int cc = c + r;
        po[r] = (mm[r] - gb_rm[cc]) / sqrtf(gb_rv[cc] + EPSV) * gb_g[cc] +
                gb_b[cc];
      }
      *(float4*)(out + (size_t)b * 43008 + c) = o4;
    }
  } else {
    // ---- BN fold ----
    int i = (blk - 18432) * 256 + t;  // [0, 36864)
    int z = i >= 18432;
    int f = i - z * 18432;
    int d = f & 2047;
    const float* g = z ? g2 : g1;
    const float* be = z ? be2 : be1;
    const float* rm = z ? rm2 : rm1;
    const float* rv = z ? rv2 : rv1;
    const float* bias = z ? b2 : b1;
    float sc = g[f] / sqrtf(rv[f] + EPSV);
    float sh = (bias[d] - rm[f]) * sc + be[f];
    (z ? sc2 : sc1)[f] = sc;
    (z ? sh2 : sh1)[f] = sh;
  }
}

// ---------------- GEMM: S[M,N] = A[M,K] @ Wt[N,K]^T  (bf16 MFMA) -----------
// 128x64 tile, BK=64 double-buffered, split-K=2. mlimit guards stores for
// the padded last M-tile (layer 1: M=576, grid 32x5x2; layer 2: M=1152,
// grid 32x9x2). XOR-swizzled staging on the global source address.
#define SPART (1152 * 2048)
__global__ __launch_bounds__(256) void gemm_db(
    const unsigned short* __restrict__ A, const unsigned short* __restrict__ Bt,
    float* __restrict__ S, int mlimit) {
  __shared__ unsigned short As[2][128 * 64];
  __shared__ unsigned short Bs[2][64 * 64];
  const int tid = threadIdx.x;
  const int lane = tid & 63;
  const int wave = tid >> 6;
  const int wm = (wave >> 1) << 6;  // 0,64
  const int wn = (wave & 1) << 5;   // 0,32
  const int quad = lane >> 4;
  const int l16 = lane & 15;
  const int by = blockIdx.y;
  const int bx = blockIdx.x;
  const int kz = blockIdx.z;

  const unsigned short* Ag = A + (size_t)by * 128 * GK;
  const unsigned short* Bg = Bt + (size_t)bx * 64 * GK;
  S += (size_t)kz * SPART;

  f32x4 acc[4][2];
#pragma unroll
  for (int i = 0; i < 4; i++)
#pragma unroll
    for (int j = 0; j < 2; j++) acc[i][j] = (f32x4){0.f, 0.f, 0.f, 0.f};

  int srA[4], scA[4];
#pragma unroll
  for (int s = 0; s < 4; s++) {
    int idx = tid + s * 256;
    srA[s] = idx >> 3;
    scA[s] = ((idx & 7) ^ (srA[s] & 7)) * 8;
  }
  int srB[2], scB[2];
#pragma unroll
  for (int s = 0; s < 2; s++) {
    int idx = tid + s * 256;
    srB[s] = idx >> 3;
    scB[s] = ((idx & 7) ^ (srB[s] & 7)) * 8;
  }

  const int kbeg = kz * 1024;

#define STAGE(buf, kk)                                                        \
  do {                                                                        \
    _Pragma("unroll") for (int s = 0; s < 4; s++) {                           \
      int idx = tid + s * 256;                                                \
      async_copy16(Ag + (size_t)srA[s] * GK + (kk) + scA[s],                  \
                   &As[buf][idx * 8]);                                        \
    }                                                                         \
    _Pragma("unroll") for (int s = 0; s < 2; s++) {                           \
      int idx = tid + s * 256;                                                \
      async_copy16(Bg + (size_t)srB[s] * GK + (kk) + scB[s],                  \
                   &Bs[buf][idx * 8]);                                        \
    }                                                                         \
  } while (0)

  STAGE(0, kbeg);
  asm volatile("s_waitcnt vmcnt(0)" ::: "memory");
  __syncthreads();

  for (int it = 0; it < 16; it++) {
    const int cur = it & 1;
    if (it < 15) STAGE(cur ^ 1, kbeg + (it + 1) * 64);

#pragma unroll
    for (int ks = 0; ks < 2; ks++) {
      bf16x8 af[4], bfr[2];
#pragma unroll
      for (int i = 0; i < 4; i++) {
        int row = wm + i * 16 + l16;
        int slot = row * 8 + ((ks * 4 + quad) ^ (row & 7));
        af[i] = *(const bf16x8*)&As[cur][slot * 8];
      }
#pragma unroll
      for (int j = 0; j < 2; j++) {
        int row = wn + j * 16 + l16;
        int slot = row * 8 + ((ks * 4 + quad) ^ (row & 7));
        bfr[j] = *(const bf16x8*)&Bs[cur][slot * 8];
      }
#pragma unroll
      for (int i = 0; i < 4; i++)
#pragma unroll
        for (int j = 0; j < 2; j++)
          acc[i][j] = __builtin_amdgcn_mfma_f32_16x16x32_bf16(
              af[i], bfr[j], acc[i][j], 0, 0, 0);
    }

    if (it < 15) {
      asm volatile("s_waitcnt vmcnt(0)" ::: "memory");
      __syncthreads();
    }
  }
#undef STAGE

#pragma unroll
  for (int i = 0; i < 4; i++)
#pragma unroll
    for (int j = 0; j < 2; j++)
#pragma unroll
      for (int r = 0; r < 4; r++) {
        int m = by * 128 + wm + i * 16 + quad * 4 + r;
        int n = bx * 64 + wn + j * 16 + l16;
        if (m < mlimit) S[(size_t)m * 2048 + n] = acc[i][j][r];
      }
}

// ---------------- Epilogue 1: adj-mix (both branches) + BN + ReLU ----------
// Reads only the MEAN-branch S (64 batches x 9 parts); self branch derived
// via rank-1 correction o_self[p] = o_mean[p] - adj[p,dm1]*s[dm1]
// (self pooled rows == mean rows except row dm1 == 0).
__global__ __launch_bounds__(256) void epi_mid(
    const float* __restrict__ S, const float* __restrict__ adj,
    const int* __restrict__ dropm1, const float* __restrict__ sc,
    const float* __restrict__ sh, unsigned short* __restrict__ Aout) {
  int idx = blockIdx.x * 256 + threadIdx.x;  // over 64*2048
  int d = idx & 2047;
  int b = idx >> 11;
  float s[9];
#pragma unroll
  for (int q = 0; q < 9; q++) {
    size_t off = (size_t)(b * 9 + q) * 2048 + d;
    s[q] = S[off] + S[off + SPART];
  }
  int dm1 = dropm1[b];
  float sd = s[dm1];
#pragma unroll
  for (int p = 0; p < 9; p++) {
    float o = 0.f;
#pragma unroll
    for (int q = 0; q < 9; q++) o += adj[b * 81 + p * 9 + q] * s[q];
    float os = o - adj[b * 81 + p * 9 + dm1] * sd;
    int f = p * 2048 + d;
    float scv = sc[f], shv = sh[f];
    Aout[(size_t)(b * 9 + p) * 2048 + d] = f2bf(fmaxf(o * scv + shv, 0.f));
    Aout[(size_t)((64 + b) * 9 + p) * 2048 + d] =
        f2bf(fmaxf(os * scv + shv, 0.f));
  }
}

// ---------------- Epilogue 2: adj-mix + folded BN + ReLU -> cats, means, BN -
__global__ __launch_bounds__(256) void epi_final(
    const float* __restrict__ S, const float* __restrict__ adj,
    const float* __restrict__ sc, const float* __restrict__ sh,
    const float* __restrict__ gn_g, const float* __restrict__ gn_b,
    const float* __restrict__ gn_rm, const float* __restrict__ gn_rv,
    float* __restrict__ out) {
  int idx = blockIdx.x * 256 + threadIdx.x;
  int d = idx & 2047;
  int bb = idx >> 11;
  int b = bb & 63;
  bool selfb = bb >= 64;
  float s[9];
#pragma unroll
  for (int q = 0; q < 9; q++) {
    size_t off = (size_t)(bb * 9 + q) * 2048 + d;
    s[q] = S[off] + S[off + SPART];
  }
  float* orow = out + (size_t)b * 43008;
  size_t catbase = selfb ? 24576 : 6144;
  float mean = 0.f;
#pragma unroll
  for (int p = 0; p < 9; p++) {
    float o = 0.f;
#pragma unroll
    for (int q = 0; q < 9; q++) o += adj[b * 81 + p * 9 + q] * s[q];
    int f = p * 2048 + d;
    float v = fmaxf(o * sc[f] + sh[f], 0.f);
    mean += v;
    orow[catbase + f] = v;
  }
  mean *= (1.f / 9.f);
  orow[(selfb ? 4096 : 2048) + d] =
      (mean - gn_rm[d]) / sqrtf(gn_rv[d] + EPSV) * gn_g[d] + gn_b[d];
}

extern "C" void kernel_launch(void* const* d_in, const int* in_sizes, int n_in,
                              void* d_out, int out_size, void* d_ws,
                              size_t ws_size, hipStream_t stream) {
  const float* x_global = (const float*)d_in[0];
  const float* x_gcn = (const float*)d_in[1];
  const int* mask = (const int*)d_in[2];
  const float* adj = (const float*)d_in[3];
  const float* W1 = (const float*)d_in[4];
  const float* b1 = (const float*)d_in[5];
  const float* g1 = (const float*)d_in[6];
  const float* be1 = (const float*)d_in[7];
  const float* rm1 = (const float*)d_in[8];
  const float* rv1 = (const float*)d_in[9];
  const float* W2 = (const float*)d_in[10];
  const float* b2 = (const float*)d_in[11];
  const float* g2 = (const float*)d_in[12];
  const float* be2 = (const float*)d_in[13];
  const float* rm2 = (const float*)d_in[14];
  const float* rv2 = (const float*)d_in[15];
  const float* gb_g = (const float*)d_in[16];
  const float* gb_b = (const float*)d_in[17];
  const float* gb_rm = (const float*)d_in[18];
  const float* gb_rv = (const float*)d_in[19];
  const float* gn_g = (const float*)d_in[20];
  const float* gn_b = (const float*)d_in[21];
  const float* gn_rm = (const float*)d_in[22];
  const float* gn_rv = (const float*)d_in[23];
  float* out = (float*)d_out;

  char* ws = (char*)d_ws;
  unsigned short* Abuf = (unsigned short*)(ws);             // 4,718,592 B
  unsigned short* Wt1 = (unsigned short*)(ws + 4718592);    // 8,388,608 B
  unsigned short* Wt2 = (unsigned short*)(ws + 13107200);   // 8,388,608 B
  float* S = (float*)(ws + 21495808);                       // 18,874,368 B
  float* sc1 = (float*)(ws + 40370176);                     // 73,728 B each
  float* sh1 = (float*)(ws + 40443904);
  float* sc2 = (float*)(ws + 40517632);
  float* sh2 = (float*)(ws + 40591360);
  int* dropm1 = (int*)(ws + 40665088);                      // 256 B

  ingest<<<18576, 256, 0, stream>>>(x_gcn, mask, Abuf, dropm1, W1, W2, Wt1,
                                    Wt2, x_global, gb_g, gb_b, gb_rm, gb_rv,
                                    out, b1, g1, be1, rm1, rv1, b2, g2, be2,
                                    rm2, rv2, sc1, sh1, sc2, sh2);
  gemm_db<<<dim3(32, 5, 2), 256, 0, stream>>>(Abuf, Wt1, S, 576);
  epi_mid<<<512, 256, 0, stream>>>(S, adj, dropm1, sc1, sh1, Abuf);
  gemm_db<<<dim3(32, 9, 2), 256, 0, stream>>>(Abuf, Wt2, S, 1152);
  epi_final<<<1024, 256, 0, stream>>>(S, adj, sc2, sh2, gn_g, gn_b, gn_rm,
                                      gn_rv, out);
}